// Round 1
// baseline (610.425 us; speedup 1.0000x reference)
//
#include <hip/hip_runtime.h>
#include <hip/hip_bf16.h>
#include <cstdint>
#include <cstddef>

typedef __bf16 bf16_t;
typedef __bf16 bf16x8 __attribute__((ext_vector_type(8)));
typedef __bf16 bf16x4 __attribute__((ext_vector_type(4)));
typedef float f32x4 __attribute__((ext_vector_type(4)));

#define MFMA16(a, b, c) __builtin_amdgcn_mfma_f32_16x16x32_bf16((a), (b), (c), 0, 0, 0)

__device__ __forceinline__ void gload_lds16(const void* g, void* l) {
  __builtin_amdgcn_global_load_lds((__attribute__((address_space(1))) void*)(g),
                                   (__attribute__((address_space(3))) void*)(l),
                                   16, 0, 0);
}

// ---------------------------------------------------------------- cvt x fp32->bf16
__global__ __launch_bounds__(256) void cvt_f32_to_bf16(const float* __restrict__ in,
                                                       bf16_t* __restrict__ out) {
  size_t i = ((size_t)blockIdx.x * 256 + threadIdx.x) * 4;
  float4 v = *(const float4*)(in + i);
  bf16x4 o = {(bf16_t)v.x, (bf16_t)v.y, (bf16_t)v.z, (bf16_t)v.w};
  *(bf16x4*)(out + i) = o;
}

// ---------------------------------------------------------------- weight transpose fp32 (R,C) -> bf16 (C,R)
__global__ __launch_bounds__(256) void transpose_w(const float* __restrict__ in,
                                                   bf16_t* __restrict__ out, int R, int C) {
  __shared__ bf16_t tile[32][33];
  int c0 = blockIdx.x * 32, r0 = blockIdx.y * 32;
  int tx = threadIdx.x, ty = threadIdx.y;
#pragma unroll
  for (int s = 0; s < 4; s++) {
    int r = ty + s * 8;
    tile[r][tx] = (bf16_t)in[(size_t)(r0 + r) * C + c0 + tx];
  }
  __syncthreads();
#pragma unroll
  for (int s = 0; s < 4; s++) {
    int r = ty + s * 8;
    out[(size_t)(c0 + r) * R + r0 + tx] = tile[tx][r];
  }
}

// ---------------------------------------------------------------- v (4096,3072) -> vt (b,h,192,2048)
__global__ __launch_bounds__(256) void transpose_v_kernel(const bf16_t* __restrict__ v,
                                                          bf16_t* __restrict__ vt) {
  __shared__ bf16_t tile[32][33];
  int bh = blockIdx.z;
  int t0 = blockIdx.x * 32, d0 = blockIdx.y * 32;
  int tx = threadIdx.x, ty = threadIdx.y;
  const bf16_t* src = v + (size_t)(bh >> 4) * 2048 * 3072 + (bh & 15) * 192;
#pragma unroll
  for (int s = 0; s < 4; s++) {
    int t = ty + s * 8;
    tile[t][tx] = src[(size_t)(t0 + t) * 3072 + d0 + tx];
  }
  __syncthreads();
  bf16_t* dst = vt + (size_t)bh * 192 * 2048;
#pragma unroll
  for (int s = 0; s < 4; s++) {
    int d = ty + s * 8;
    dst[(size_t)(d0 + d) * 2048 + t0 + tx] = tile[tx][d];
  }
}

// ---------------------------------------------------------------- rope in-place on packed (4096, 16*192) buffer
__global__ __launch_bounds__(256) void rope_inplace(bf16_t* __restrict__ buf) {
  int idx = blockIdx.x * 256 + threadIdx.x;
  int j = idx & 31;
  int h = (idx >> 5) & 15;
  int row = idx >> 9;           // 0..4095
  int t = row & 2047;
  size_t base = (size_t)row * 3072 + h * 192 + 128;
  // inv = theta^(-j/32) = exp(-j * ln(10000)/32)
  float inv = expf(-(float)j * 0.28782313662425574f);
  float ang = (float)t * inv;
  float c, s;
  sincosf(ang, &s, &c);
  float x1 = (float)buf[base + j];
  float x2 = (float)buf[base + j + 32];
  buf[base + j]      = (bf16_t)(x1 * c - x2 * s);
  buf[base + j + 32] = (bf16_t)(x1 * s + x2 * c);
}

// ---------------------------------------------------------------- GEMM: C = A(M,K) * Bt(N,K)^T
// 128x128 tile, BK=64, 4 waves (2x2), each wave 64x64 = 4x4 frags of 16x16x32.
// MODE 0: bf16 out, col=n.  MODE 1: f32 out, col=n.
// MODE 2: bf16 out, col=(n>>7)*192+(n&127)   (q_c/k_c head split, CD=128)
// MODE 3: bf16 out, col=(n>>6)*192+128+(n&63) (q_p/k_p rope split, RD=64)
template <int MODE>
__global__ __launch_bounds__(256) void gemm_bt(const bf16_t* __restrict__ A,
                                               const bf16_t* __restrict__ Bt,
                                               void* __restrict__ Cout, int K, int ldc) {
  __shared__ __align__(16) bf16_t sA[128 * 64];
  __shared__ __align__(16) bf16_t sB[128 * 64];
  const int tid = threadIdx.x;
  const int l = tid & 63, w = tid >> 6;
  const int l15 = l & 15, l4 = l >> 4;
  const int wr = w >> 1, wc = w & 1;
  const int m0 = blockIdx.y * 128, n0 = blockIdx.x * 128;

  f32x4 acc[4][4] = {};

  for (int kt = 0; kt < K; kt += 64) {
#pragma unroll
    for (int r = 0; r < 4; r++) {
      int i = r * 256 + tid;
      int row = i >> 3, cl = i & 7;
      int cg = cl ^ (row & 7);  // pre-swizzled global source, linear LDS dest
      const bf16_t* srcA = A + (size_t)(m0 + row) * K + kt + cg * 8;
      const bf16_t* srcB = Bt + (size_t)(n0 + row) * K + kt + cg * 8;
      char* dstA = (char*)sA + (size_t)(r * 256 + w * 64) * 16;
      char* dstB = (char*)sB + (size_t)(r * 256 + w * 64) * 16;
      gload_lds16(srcA, dstA);
      gload_lds16(srcB, dstB);
    }
    __syncthreads();
#pragma unroll
    for (int ks = 0; ks < 2; ks++) {
      bf16x8 af[4], bfr[4];
#pragma unroll
      for (int mf = 0; mf < 4; mf++) {
        int row = wr * 64 + mf * 16 + l15;
        int cl = (ks * 4 + l4) ^ (row & 7);
        af[mf] = *(const bf16x8*)(sA + row * 64 + cl * 8);
      }
#pragma unroll
      for (int nf = 0; nf < 4; nf++) {
        int row = wc * 64 + nf * 16 + l15;
        int cl = (ks * 4 + l4) ^ (row & 7);
        bfr[nf] = *(const bf16x8*)(sB + row * 64 + cl * 8);
      }
#pragma unroll
      for (int mf = 0; mf < 4; mf++)
#pragma unroll
        for (int nf = 0; nf < 4; nf++)
          acc[mf][nf] = MFMA16(af[mf], bfr[nf], acc[mf][nf]);
    }
    __syncthreads();
  }

#pragma unroll
  for (int mf = 0; mf < 4; mf++)
#pragma unroll
    for (int nf = 0; nf < 4; nf++)
#pragma unroll
      for (int r = 0; r < 4; r++) {
        int m = m0 + wr * 64 + mf * 16 + l4 * 4 + r;
        int n = n0 + wc * 64 + nf * 16 + l15;
        float v = acc[mf][nf][r];
        if constexpr (MODE == 1) {
          ((float*)Cout)[(size_t)m * ldc + n] = v;
        } else {
          int col;
          if constexpr (MODE == 0) col = n;
          else if constexpr (MODE == 2) col = (n >> 7) * 192 + (n & 127);
          else col = (n >> 6) * 192 + 128 + (n & 63);
          ((bf16_t*)Cout)[(size_t)m * ldc + col] = (bf16_t)v;
        }
      }
}

// ---------------------------------------------------------------- flash attention (causal)
// q,k: (B*T, 16*192) packed; vt: (b,h,192,2048); ao: (B*T, 3072)
// block: 4 waves, 128 q-rows (32/wave); K-tile = 64.
__global__ __launch_bounds__(256) void attn_kernel(const bf16_t* __restrict__ q,
                                                   const bf16_t* __restrict__ kbuf,
                                                   const bf16_t* __restrict__ vt,
                                                   bf16_t* __restrict__ ao) {
  __shared__ __align__(16) bf16_t sK[64][192];  // perm-24 swizzle; first 16KB reused as P
  __shared__ __align__(16) bf16_t sV[192][64];  // xor-8 chunk swizzle
  bf16_t* sP = &sK[0][0];

  const int tid = threadIdx.x, l = tid & 63, w = tid >> 6;
  const int l15 = l & 15, l4 = l >> 4;
  const int bh = blockIdx.y, b = bh >> 4, h = bh & 15;
  const int q0 = blockIdx.x * 128;
  const int qw0 = q0 + w * 32;

  const bf16_t* qp = q + (size_t)b * 2048 * 3072 + h * 192;
  const bf16_t* kp = kbuf + (size_t)b * 2048 * 3072 + h * 192;
  const bf16_t* vp = vt + (size_t)bh * 192 * 2048;

  bf16x8 qf[2][6];
#pragma unroll
  for (int mf = 0; mf < 2; mf++)
#pragma unroll
    for (int kd = 0; kd < 6; kd++)
      qf[mf][kd] = *(const bf16x8*)(qp + (size_t)(qw0 + mf * 16 + l15) * 3072 + kd * 32 + l4 * 8);

  f32x4 o[2][12] = {};
  float mrow[2][4], lrow[2][4];
#pragma unroll
  for (int mf = 0; mf < 2; mf++)
#pragma unroll
    for (int r = 0; r < 4; r++) {
      mrow[mf][r] = -__builtin_inff();
      lrow[mf][r] = 0.0f;
    }

  const float scale = 0.07216878364870322f;  // 1/sqrt(192)
  const int nkt = q0 / 64 + 2;

  for (int kt = 0; kt < nkt; kt++) {
    const int k0 = kt * 64;
    __syncthreads();  // protect LDS (K/P and V) from previous iteration readers
    // stage K tile [64][192], perm-24: LDS(row,cc) holds global chunk (cc - 3*(row&7)) mod 24
#pragma unroll
    for (int r = 0; r < 6; r++) {
      int i = r * 256 + tid;
      int row = i / 24, cc = i - row * 24;
      int g = cc - (row & 7) * 3;
      if (g < 0) g += 24;
      *(bf16x8*)(&sK[row][cc * 8]) = *(const bf16x8*)(kp + (size_t)(k0 + row) * 3072 + g * 8);
    }
    // stage V tile [192][64], xor-8: LDS(d,cc) holds global chunk cc^(d&7)
#pragma unroll
    for (int r = 0; r < 6; r++) {
      int i = r * 256 + tid;
      int d = i >> 3, cc = i & 7;
      *(bf16x8*)(&sV[d][cc * 8]) = *(const bf16x8*)(vp + (size_t)d * 2048 + k0 + (cc ^ (d & 7)) * 8);
    }
    __syncthreads();

    // S = Q K^T
    f32x4 s[2][4] = {};
#pragma unroll
    for (int kd = 0; kd < 6; kd++) {
      bf16x8 bk[4];
#pragma unroll
      for (int nf = 0; nf < 4; nf++) {
        int row = nf * 16 + l15;
        int cl = kd * 4 + l4 + (row & 7) * 3;
        if (cl >= 24) cl -= 24;
        bk[nf] = *(const bf16x8*)(&sK[row][cl * 8]);
      }
#pragma unroll
      for (int mf = 0; mf < 2; mf++)
#pragma unroll
        for (int nf = 0; nf < 4; nf++)
          s[mf][nf] = MFMA16(qf[mf][kd], bk[nf], s[mf][nf]);
    }
    __syncthreads();  // all waves done reading sK before P overwrites it

    // scale + causal mask
#pragma unroll
    for (int mf = 0; mf < 2; mf++)
#pragma unroll
      for (int nf = 0; nf < 4; nf++)
#pragma unroll
        for (int r = 0; r < 4; r++) {
          int qg = qw0 + mf * 16 + l4 * 4 + r;
          int kg = k0 + nf * 16 + l15;
          float sv = s[mf][nf][r] * scale;
          s[mf][nf][r] = (kg > qg) ? -__builtin_inff() : sv;
        }
    // row max (across nf, then across 16 lanes)
    float mnew[2][4];
#pragma unroll
    for (int mf = 0; mf < 2; mf++)
#pragma unroll
      for (int r = 0; r < 4; r++) {
        float v = s[mf][0][r];
        v = fmaxf(v, s[mf][1][r]);
        v = fmaxf(v, s[mf][2][r]);
        v = fmaxf(v, s[mf][3][r]);
        mnew[mf][r] = v;
      }
#pragma unroll
    for (int d = 1; d < 16; d <<= 1)
#pragma unroll
      for (int mf = 0; mf < 2; mf++)
#pragma unroll
        for (int r = 0; r < 4; r++)
          mnew[mf][r] = fmaxf(mnew[mf][r], __shfl_xor(mnew[mf][r], d));

    float alpha[2][4];
#pragma unroll
    for (int mf = 0; mf < 2; mf++)
#pragma unroll
      for (int r = 0; r < 4; r++) {
        float mi = fmaxf(mrow[mf][r], mnew[mf][r]);
        alpha[mf][r] = __expf(mrow[mf][r] - mi);
        mrow[mf][r] = mi;
      }
    // p = exp(s - m), row sums
    float rs[2][4] = {};
#pragma unroll
    for (int mf = 0; mf < 2; mf++)
#pragma unroll
      for (int nf = 0; nf < 4; nf++)
#pragma unroll
        for (int r = 0; r < 4; r++) {
          float p = __expf(s[mf][nf][r] - mrow[mf][r]);
          s[mf][nf][r] = p;
          rs[mf][r] += p;
        }
#pragma unroll
    for (int d = 1; d < 16; d <<= 1)
#pragma unroll
      for (int mf = 0; mf < 2; mf++)
#pragma unroll
        for (int r = 0; r < 4; r++)
          rs[mf][r] += __shfl_xor(rs[mf][r], d);
#pragma unroll
    for (int mf = 0; mf < 2; mf++)
#pragma unroll
      for (int r = 0; r < 4; r++)
        lrow[mf][r] = lrow[mf][r] * alpha[mf][r] + rs[mf][r];
    // rescale O
#pragma unroll
    for (int mf = 0; mf < 2; mf++)
#pragma unroll
      for (int nf2 = 0; nf2 < 12; nf2++)
#pragma unroll
        for (int r = 0; r < 4; r++)
          o[mf][nf2][r] *= alpha[mf][r];

    // write P (bf16) into sP (aliases sK), xor-8 chunk swizzle on [32][64] rows
    bf16_t* sPw = sP + w * (32 * 64);
#pragma unroll
    for (int mf = 0; mf < 2; mf++)
#pragma unroll
      for (int nf = 0; nf < 4; nf++)
#pragma unroll
        for (int r = 0; r < 4; r++) {
          int prow = mf * 16 + l4 * 4 + r;
          int col = nf * 16 + l15;
          int ch = (col >> 3) ^ (prow & 7);
          sPw[prow * 64 + ch * 8 + (col & 7)] = (bf16_t)s[mf][nf][r];
        }
    asm volatile("s_waitcnt lgkmcnt(0)" ::: "memory");
    __builtin_amdgcn_sched_barrier(0);

    // O += P V
#pragma unroll
    for (int ks = 0; ks < 2; ks++) {
      bf16x8 pa[2];
#pragma unroll
      for (int mf = 0; mf < 2; mf++) {
        int prow = mf * 16 + l15;
        int cl = (ks * 4 + l4) ^ (prow & 7);
        pa[mf] = *(const bf16x8*)(sPw + prow * 64 + cl * 8);
      }
#pragma unroll
      for (int nf2 = 0; nf2 < 12; nf2++) {
        int d = nf2 * 16 + l15;
        int cl = (ks * 4 + l4) ^ (d & 7);
        bf16x8 vb = *(const bf16x8*)(&sV[d][cl * 8]);
#pragma unroll
        for (int mf = 0; mf < 2; mf++)
          o[mf][nf2] = MFMA16(pa[mf], vb, o[mf][nf2]);
      }
    }
  }

  // epilogue: O/l -> ao (b*T+q, h*192+d)
#pragma unroll
  for (int mf = 0; mf < 2; mf++)
#pragma unroll
    for (int r = 0; r < 4; r++) {
      float inv = 1.0f / lrow[mf][r];
      int qrow = qw0 + mf * 16 + l4 * 4 + r;
#pragma unroll
      for (int nf2 = 0; nf2 < 12; nf2++) {
        int d = nf2 * 16 + l15;
        ao[(size_t)(b * 2048 + qrow) * 3072 + h * 192 + d] = (bf16_t)(o[mf][nf2][r] * inv);
      }
    }
}

// ----------------------------------------------------------------
extern "C" void kernel_launch(void* const* d_in, const int* in_sizes, int n_in,
                              void* d_out, int out_size, void* d_ws, size_t ws_size,
                              hipStream_t stream) {
  const float* x       = (const float*)d_in[0];
  const float* wq_down = (const float*)d_in[1];
  const float* wq_up   = (const float*)d_in[2];
  const float* wq_rope = (const float*)d_in[3];
  const float* wkv_down= (const float*)d_in[4];
  const float* wk_up   = (const float*)d_in[5];
  const float* wv_up   = (const float*)d_in[6];
  const float* wk_rope = (const float*)d_in[7];
  const float* wo      = (const float*)d_in[8];
  float* out = (float*)d_out;

  char* p = (char*)d_ws;
  auto take = [&](size_t elems) { bf16_t* r = (bf16_t*)p; p += elems * 2; return r; };
  bf16_t* xb     = take(4096ull * 2048);
  bf16_t* wqd_t  = take(768ull * 2048);
  bf16_t* wqu_t  = take(2048ull * 768);
  bf16_t* wqr_t  = take(1024ull * 2048);
  bf16_t* wkvd_t = take(512ull * 2048);
  bf16_t* wku_t  = take(2048ull * 512);
  bf16_t* wvu_t  = take(3072ull * 512);
  bf16_t* wkr_t  = take(1024ull * 2048);
  bf16_t* wo_t   = take(2048ull * 3072);
  bf16_t* qdown  = take(4096ull * 768);
  bf16_t* latent = take(4096ull * 512);
  bf16_t* qbuf   = take(4096ull * 3072);
  bf16_t* kbuf   = take(4096ull * 3072);
  bf16_t* vbuf   = take(4096ull * 3072);
  bf16_t* vt     = take(4096ull * 3072);
  bf16_t* ao     = vbuf;  // v row-major dead after transpose_v; reuse for attention out

  dim3 tb(32, 8);
  cvt_f32_to_bf16<<<8192, 256, 0, stream>>>(x, xb);
  transpose_w<<<dim3(768 / 32, 2048 / 32), tb, 0, stream>>>(wq_down, wqd_t, 2048, 768);
  transpose_w<<<dim3(2048 / 32, 768 / 32), tb, 0, stream>>>(wq_up, wqu_t, 768, 2048);
  transpose_w<<<dim3(1024 / 32, 2048 / 32), tb, 0, stream>>>(wq_rope, wqr_t, 2048, 1024);
  transpose_w<<<dim3(512 / 32, 2048 / 32), tb, 0, stream>>>(wkv_down, wkvd_t, 2048, 512);
  transpose_w<<<dim3(2048 / 32, 512 / 32), tb, 0, stream>>>(wk_up, wku_t, 512, 2048);
  transpose_w<<<dim3(3072 / 32, 512 / 32), tb, 0, stream>>>(wv_up, wvu_t, 512, 3072);
  transpose_w<<<dim3(1024 / 32, 2048 / 32), tb, 0, stream>>>(wk_rope, wkr_t, 2048, 1024);
  transpose_w<<<dim3(2048 / 32, 3072 / 32), tb, 0, stream>>>(wo, wo_t, 3072, 2048);

  gemm_bt<0><<<dim3(6, 32), 256, 0, stream>>>(xb, wqd_t, qdown, 2048, 768);
  gemm_bt<0><<<dim3(4, 32), 256, 0, stream>>>(xb, wkvd_t, latent, 2048, 512);
  gemm_bt<2><<<dim3(16, 32), 256, 0, stream>>>(qdown, wqu_t, qbuf, 768, 3072);
  gemm_bt<3><<<dim3(8, 32), 256, 0, stream>>>(xb, wqr_t, qbuf, 2048, 3072);
  gemm_bt<2><<<dim3(16, 32), 256, 0, stream>>>(latent, wku_t, kbuf, 512, 3072);
  gemm_bt<3><<<dim3(8, 32), 256, 0, stream>>>(xb, wkr_t, kbuf, 2048, 3072);
  gemm_bt<0><<<dim3(24, 32), 256, 0, stream>>>(latent, wvu_t, vbuf, 512, 3072);

  rope_inplace<<<8192, 256, 0, stream>>>(qbuf);
  rope_inplace<<<8192, 256, 0, stream>>>(kbuf);
  transpose_v_kernel<<<dim3(64, 6, 32), tb, 0, stream>>>(vbuf, vt);

  attn_kernel<<<dim3(16, 32), 256, 0, stream>>>(qbuf, kbuf, vt, ao);

  gemm_bt<1><<<dim3(16, 32), 256, 0, stream>>>(ao, wo_t, out, 3072, 2048);
}

// Round 2
// 476.358 us; speedup vs baseline: 1.2814x; 1.2814x over previous
//
#include <hip/hip_runtime.h>
#include <hip/hip_bf16.h>
#include <cstdint>
#include <cstddef>

typedef __bf16 bf16_t;
typedef __bf16 bf16x8 __attribute__((ext_vector_type(8)));
typedef __bf16 bf16x4 __attribute__((ext_vector_type(4)));
typedef float f32x4 __attribute__((ext_vector_type(4)));

#define MFMA16(a, b, c) __builtin_amdgcn_mfma_f32_16x16x32_bf16((a), (b), (c), 0, 0, 0)

__device__ __forceinline__ void gload_lds16(const void* g, void* l) {
  __builtin_amdgcn_global_load_lds((__attribute__((address_space(1))) void*)(g),
                                   (__attribute__((address_space(3))) void*)(l),
                                   16, 0, 0);
}

// ---------------------------------------------------------------- cvt x fp32->bf16
__global__ __launch_bounds__(256) void cvt_f32_to_bf16(const float* __restrict__ in,
                                                       bf16_t* __restrict__ out) {
  size_t i = ((size_t)blockIdx.x * 256 + threadIdx.x) * 4;
  float4 v = *(const float4*)(in + i);
  bf16x4 o = {(bf16_t)v.x, (bf16_t)v.y, (bf16_t)v.z, (bf16_t)v.w};
  *(bf16x4*)(out + i) = o;
}

// ---------------------------------------------------------------- weight transpose fp32 (R,C) -> bf16 (C,R)
__global__ __launch_bounds__(256) void transpose_w(const float* __restrict__ in,
                                                   bf16_t* __restrict__ out, int R, int C) {
  __shared__ bf16_t tile[32][33];
  int c0 = blockIdx.x * 32, r0 = blockIdx.y * 32;
  int tx = threadIdx.x, ty = threadIdx.y;
#pragma unroll
  for (int s = 0; s < 4; s++) {
    int r = ty + s * 8;
    tile[r][tx] = (bf16_t)in[(size_t)(r0 + r) * C + c0 + tx];
  }
  __syncthreads();
#pragma unroll
  for (int s = 0; s < 4; s++) {
    int r = ty + s * 8;
    out[(size_t)(c0 + r) * R + r0 + tx] = tile[tx][r];
  }
}

// ---------------------------------------------------------------- v (4096,3072) -> vt (b,h,192,2048)
__global__ __launch_bounds__(256) void transpose_v_kernel(const bf16_t* __restrict__ v,
                                                          bf16_t* __restrict__ vt) {
  __shared__ bf16_t tile[32][33];
  int bh = blockIdx.z;
  int t0 = blockIdx.x * 32, d0 = blockIdx.y * 32;
  int tx = threadIdx.x, ty = threadIdx.y;
  const bf16_t* src = v + (size_t)(bh >> 4) * 2048 * 3072 + (bh & 15) * 192;
#pragma unroll
  for (int s = 0; s < 4; s++) {
    int t = ty + s * 8;
    tile[t][tx] = src[(size_t)(t0 + t) * 3072 + d0 + tx];
  }
  __syncthreads();
  bf16_t* dst = vt + (size_t)bh * 192 * 2048;
#pragma unroll
  for (int s = 0; s < 4; s++) {
    int d = ty + s * 8;
    dst[(size_t)(d0 + d) * 2048 + t0 + tx] = tile[tx][d];
  }
}

// ---------------------------------------------------------------- rope in-place on packed (4096, 16*192) buffer
__global__ __launch_bounds__(256) void rope_inplace(bf16_t* __restrict__ buf) {
  int idx = blockIdx.x * 256 + threadIdx.x;
  int j = idx & 31;
  int h = (idx >> 5) & 15;
  int row = idx >> 9;           // 0..4095
  int t = row & 2047;
  size_t base = (size_t)row * 3072 + h * 192 + 128;
  float inv = expf(-(float)j * 0.28782313662425574f);
  float ang = (float)t * inv;
  float c, s;
  sincosf(ang, &s, &c);
  float x1 = (float)buf[base + j];
  float x2 = (float)buf[base + j + 32];
  buf[base + j]      = (bf16_t)(x1 * c - x2 * s);
  buf[base + j + 32] = (bf16_t)(x1 * s + x2 * c);
}

// ---------------------------------------------------------------- GEMM: C = A(M,lda) [:, :K] * Bt(N,K)^T
// 128x128 tile, BK=64, 4 waves (2x2), each wave 64x64 = 4x4 frags of 16x16x32.
// MODE 1: f32 out to C0 (ldc).
// MODE 2: bf16 head-split CD to C0: col=(n>>7)*192+(n&127), ldc 3072.
// MODE 4: FUSE1: n<1280 -> C0 (qkvd, ldc1280) col n; n<2304 -> C1 rope col; else C2 rope col.
// MODE 5: FUSE2: n<2048 -> C0 head-split CD; else C1 (ldc 3072) col n-2048.
template <int MODE>
__global__ __launch_bounds__(256) void gemm_bt(const bf16_t* __restrict__ A, int lda,
                                               const bf16_t* __restrict__ Bt,
                                               void* __restrict__ C0, void* __restrict__ C1,
                                               void* __restrict__ C2, int K, int ldc) {
  __shared__ __align__(16) bf16_t sA[128 * 64];
  __shared__ __align__(16) bf16_t sB[128 * 64];
  const int tid = threadIdx.x;
  const int l = tid & 63, w = tid >> 6;
  const int l15 = l & 15, l4 = l >> 4;
  const int wr = w >> 1, wc = w & 1;
  const int m0 = blockIdx.y * 128, n0 = blockIdx.x * 128;

  f32x4 acc[4][4] = {};

  for (int kt = 0; kt < K; kt += 64) {
#pragma unroll
    for (int r = 0; r < 4; r++) {
      int i = r * 256 + tid;
      int row = i >> 3, cl = i & 7;
      int cg = cl ^ (row & 7);  // pre-swizzled global source, linear LDS dest
      const bf16_t* srcA = A + (size_t)(m0 + row) * lda + kt + cg * 8;
      const bf16_t* srcB = Bt + (size_t)(n0 + row) * K + kt + cg * 8;
      char* dstA = (char*)sA + (size_t)(r * 256 + w * 64) * 16;
      char* dstB = (char*)sB + (size_t)(r * 256 + w * 64) * 16;
      gload_lds16(srcA, dstA);
      gload_lds16(srcB, dstB);
    }
    __syncthreads();
#pragma unroll
    for (int ks = 0; ks < 2; ks++) {
      bf16x8 af[4], bfr[4];
#pragma unroll
      for (int mf = 0; mf < 4; mf++) {
        int row = wr * 64 + mf * 16 + l15;
        int cl = (ks * 4 + l4) ^ (row & 7);
        af[mf] = *(const bf16x8*)(sA + row * 64 + cl * 8);
      }
#pragma unroll
      for (int nf = 0; nf < 4; nf++) {
        int row = wc * 64 + nf * 16 + l15;
        int cl = (ks * 4 + l4) ^ (row & 7);
        bfr[nf] = *(const bf16x8*)(sB + row * 64 + cl * 8);
      }
#pragma unroll
      for (int mf = 0; mf < 4; mf++)
#pragma unroll
        for (int nf = 0; nf < 4; nf++)
          acc[mf][nf] = MFMA16(af[mf], bfr[nf], acc[mf][nf]);
    }
    __syncthreads();
  }

#pragma unroll
  for (int mf = 0; mf < 4; mf++)
#pragma unroll
    for (int nf = 0; nf < 4; nf++)
#pragma unroll
      for (int r = 0; r < 4; r++) {
        int m = m0 + wr * 64 + mf * 16 + l4 * 4 + r;
        int n = n0 + wc * 64 + nf * 16 + l15;
        float v = acc[mf][nf][r];
        if constexpr (MODE == 1) {
          ((float*)C0)[(size_t)m * ldc + n] = v;
        } else if constexpr (MODE == 2) {
          ((bf16_t*)C0)[(size_t)m * 3072 + (n >> 7) * 192 + (n & 127)] = (bf16_t)v;
        } else if constexpr (MODE == 4) {
          if (n < 1280) {
            ((bf16_t*)C0)[(size_t)m * 1280 + n] = (bf16_t)v;
          } else if (n < 2304) {
            int nn = n - 1280;
            ((bf16_t*)C1)[(size_t)m * 3072 + (nn >> 6) * 192 + 128 + (nn & 63)] = (bf16_t)v;
          } else {
            int nn = n - 2304;
            ((bf16_t*)C2)[(size_t)m * 3072 + (nn >> 6) * 192 + 128 + (nn & 63)] = (bf16_t)v;
          }
        } else {  // MODE 5
          if (n < 2048) {
            ((bf16_t*)C0)[(size_t)m * 3072 + (n >> 7) * 192 + (n & 127)] = (bf16_t)v;
          } else {
            ((bf16_t*)C1)[(size_t)m * 3072 + (n - 2048)] = (bf16_t)v;
          }
        }
      }
}

// ---------------------------------------------------------------- flash attention (causal, paired chunks)
// q,k: (B*T, 16*192) packed; vt: (b,h,192,2048); ao: (B*T, 3072)
// 32 q-chunks of 64 rows; block p handles chunks (p, 31-p) in one K-loop -> uniform work.
// 4 waves; wave w owns rows [16w,16w+16) of each chunk (mf = chunk selector).
__global__ __launch_bounds__(256) void attn_kernel(const bf16_t* __restrict__ q,
                                                   const bf16_t* __restrict__ kbuf,
                                                   const bf16_t* __restrict__ vt,
                                                   bf16_t* __restrict__ ao) {
  __shared__ __align__(16) bf16_t sK[64][192];  // perm-24 swizzle; first 16KB reused as P
  __shared__ __align__(16) bf16_t sV[192][64];  // xor-8 chunk swizzle
  bf16_t* sP = &sK[0][0];

  const int tid = threadIdx.x, l = tid & 63, w = tid >> 6;
  const int l15 = l & 15, l4 = l >> 4;
  const int bh = blockIdx.y, b = bh >> 4, h = bh & 15;
  const int p = blockIdx.x;
  const int ca = p, cb = 31 - p;
  const int ra = ca * 64 + w * 16;
  const int rb = cb * 64 + w * 16;

  const bf16_t* qp = q + (size_t)b * 2048 * 3072 + h * 192;
  const bf16_t* kp = kbuf + (size_t)b * 2048 * 3072 + h * 192;
  const bf16_t* vp = vt + (size_t)bh * 192 * 2048;

  bf16x8 qf[2][6];
#pragma unroll
  for (int kd = 0; kd < 6; kd++) {
    qf[0][kd] = *(const bf16x8*)(qp + (size_t)(ra + l15) * 3072 + kd * 32 + l4 * 8);
    qf[1][kd] = *(const bf16x8*)(qp + (size_t)(rb + l15) * 3072 + kd * 32 + l4 * 8);
  }

  f32x4 o[2][12] = {};
  float mrow[2][4], lrow[2][4];
#pragma unroll
  for (int mf = 0; mf < 2; mf++)
#pragma unroll
    for (int r = 0; r < 4; r++) {
      mrow[mf][r] = -__builtin_inff();
      lrow[mf][r] = 0.0f;
    }

  const float scale = 0.07216878364870322f;  // 1/sqrt(192)
  const int nkt = cb + 1;

  for (int kt = 0; kt < nkt; kt++) {
    const int k0 = kt * 64;
    const bool act_a = (kt <= ca);
    __syncthreads();  // previous iteration's sV/sP readers done before restage

    // stage K tile [64][192] via global_load_lds: linear LDS, perm-24 pre-swizzled source
#pragma unroll
    for (int r = 0; r < 6; r++) {
      int i = r * 256 + tid;
      int row = i / 24, cc = i % 24;
      int g = cc - (row & 7) * 3;
      if (g < 0) g += 24;
      gload_lds16(kp + (size_t)(k0 + row) * 3072 + g * 8,
                  (char*)sK + (size_t)(r * 256 + w * 64) * 16);
    }
    // stage V tile [192][64]: xor-8 pre-swizzled source
#pragma unroll
    for (int r = 0; r < 6; r++) {
      int i = r * 256 + tid;
      int d = i >> 3, cc = i & 7;
      gload_lds16(vp + (size_t)d * 2048 + k0 + (cc ^ (d & 7)) * 8,
                  (char*)sV + (size_t)(r * 256 + w * 64) * 16);
    }
    __syncthreads();  // implicit vmcnt(0) drain -> tiles ready

    // S = Q K^T  (chunk b always, chunk a if active)
    f32x4 s[2][4] = {};
#pragma unroll
    for (int kd = 0; kd < 6; kd++) {
      bf16x8 bk[4];
#pragma unroll
      for (int nf = 0; nf < 4; nf++) {
        int row = nf * 16 + l15;
        int cl = kd * 4 + l4 + (row & 7) * 3;
        if (cl >= 24) cl -= 24;
        bk[nf] = *(const bf16x8*)(&sK[row][cl * 8]);
      }
#pragma unroll
      for (int nf = 0; nf < 4; nf++)
        s[1][nf] = MFMA16(qf[1][kd], bk[nf], s[1][nf]);
      if (act_a) {
#pragma unroll
        for (int nf = 0; nf < 4; nf++)
          s[0][nf] = MFMA16(qf[0][kd], bk[nf], s[0][nf]);
      }
    }
    __syncthreads();  // all waves done reading sK before P overwrites it

    bf16_t* sPw = sP + w * 2048;

    auto softmax_chunk = [&](int mf, int rbase, int cid) {
      const bool diag = (kt == cid);
      // scale + causal mask (diag tile only)
#pragma unroll
      for (int nf = 0; nf < 4; nf++)
#pragma unroll
        for (int r = 0; r < 4; r++) {
          float sv = s[mf][nf][r] * scale;
          if (diag) {
            int qg = rbase + l4 * 4 + r;
            int kg = k0 + nf * 16 + l15;
            if (kg > qg) sv = -__builtin_inff();
          }
          s[mf][nf][r] = sv;
        }
      float mnew[4];
#pragma unroll
      for (int r = 0; r < 4; r++)
        mnew[r] = fmaxf(fmaxf(s[mf][0][r], s[mf][1][r]), fmaxf(s[mf][2][r], s[mf][3][r]));
#pragma unroll
      for (int d = 1; d < 16; d <<= 1)
#pragma unroll
        for (int r = 0; r < 4; r++)
          mnew[r] = fmaxf(mnew[r], __shfl_xor(mnew[r], d));
      float alpha[4];
#pragma unroll
      for (int r = 0; r < 4; r++) {
        float mi = fmaxf(mrow[mf][r], mnew[r]);
        alpha[r] = __expf(mrow[mf][r] - mi);
        mrow[mf][r] = mi;
      }
      float rs[4] = {};
#pragma unroll
      for (int nf = 0; nf < 4; nf++)
#pragma unroll
        for (int r = 0; r < 4; r++) {
          float pv = __expf(s[mf][nf][r] - mrow[mf][r]);
          s[mf][nf][r] = pv;
          rs[r] += pv;
        }
#pragma unroll
      for (int d = 1; d < 16; d <<= 1)
#pragma unroll
        for (int r = 0; r < 4; r++)
          rs[r] += __shfl_xor(rs[r], d);
#pragma unroll
      for (int r = 0; r < 4; r++)
        lrow[mf][r] = lrow[mf][r] * alpha[r] + rs[r];
#pragma unroll
      for (int nf2 = 0; nf2 < 12; nf2++)
#pragma unroll
        for (int r = 0; r < 4; r++)
          o[mf][nf2][r] *= alpha[r];
      // write P (bf16) into per-wave slot, xor-8 chunk swizzle on [16][64]
      bf16_t* sPc = sPw + mf * 1024;
#pragma unroll
      for (int nf = 0; nf < 4; nf++)
#pragma unroll
        for (int r = 0; r < 4; r++) {
          int prow = l4 * 4 + r;
          int col = nf * 16 + l15;
          int ch = (col >> 3) ^ (prow & 7);
          sPc[prow * 64 + ch * 8 + (col & 7)] = (bf16_t)s[mf][nf][r];
        }
    };

    softmax_chunk(1, rb, cb);
    if (act_a) softmax_chunk(0, ra, ca);

    asm volatile("s_waitcnt lgkmcnt(0)" ::: "memory");
    __builtin_amdgcn_sched_barrier(0);

    // O += P V
#pragma unroll
    for (int ks = 0; ks < 2; ks++) {
      bf16x8 pa[2];
      {
        int prow = l15;
        int cl = (ks * 4 + l4) ^ (prow & 7);
        pa[1] = *(const bf16x8*)(sPw + 1024 + prow * 64 + cl * 8);
        pa[0] = *(const bf16x8*)(sPw + prow * 64 + cl * 8);
      }
#pragma unroll
      for (int nf2 = 0; nf2 < 12; nf2++) {
        int d = nf2 * 16 + l15;
        int cl = (ks * 4 + l4) ^ (d & 7);
        bf16x8 vb = *(const bf16x8*)(&sV[d][cl * 8]);
        o[1][nf2] = MFMA16(pa[1], vb, o[1][nf2]);
        if (act_a) o[0][nf2] = MFMA16(pa[0], vb, o[0][nf2]);
      }
    }
  }

  // epilogue: O/l -> ao (b*T+q, h*192+d), both chunks
#pragma unroll
  for (int mf = 0; mf < 2; mf++) {
    const int rbase = (mf == 0) ? ra : rb;
#pragma unroll
    for (int r = 0; r < 4; r++) {
      float inv = 1.0f / lrow[mf][r];
      int qrow = rbase + l4 * 4 + r;
#pragma unroll
      for (int nf2 = 0; nf2 < 12; nf2++) {
        int d = nf2 * 16 + l15;
        ao[(size_t)(b * 2048 + qrow) * 3072 + h * 192 + d] = (bf16_t)(o[mf][nf2][r] * inv);
      }
    }
  }
}

// ----------------------------------------------------------------
extern "C" void kernel_launch(void* const* d_in, const int* in_sizes, int n_in,
                              void* d_out, int out_size, void* d_ws, size_t ws_size,
                              hipStream_t stream) {
  const float* x       = (const float*)d_in[0];
  const float* wq_down = (const float*)d_in[1];
  const float* wq_up   = (const float*)d_in[2];
  const float* wq_rope = (const float*)d_in[3];
  const float* wkv_down= (const float*)d_in[4];
  const float* wk_up   = (const float*)d_in[5];
  const float* wv_up   = (const float*)d_in[6];
  const float* wk_rope = (const float*)d_in[7];
  const float* wo      = (const float*)d_in[8];
  float* out = (float*)d_out;

  char* p = (char*)d_ws;
  auto take = [&](size_t elems) { bf16_t* r = (bf16_t*)p; p += elems * 2; return r; };
  bf16_t* xb    = take(4096ull * 2048);
  bf16_t* fw1   = take(3328ull * 2048);  // [wq_down(768) | wkv_down(512) | wq_rope(1024) | wk_rope(1024)]^T
  bf16_t* wqu_t = take(2048ull * 768);
  bf16_t* fw2   = take(5120ull * 512);   // [wk_up(2048) | wv_up(3072)]^T
  bf16_t* wo_t  = take(2048ull * 3072);
  bf16_t* qkvd  = take(4096ull * 1280);  // [q_down(768) | latent(512)]
  bf16_t* qbuf  = take(4096ull * 3072);
  bf16_t* kbuf  = take(4096ull * 3072);
  bf16_t* vbuf  = take(4096ull * 3072);
  bf16_t* vt    = take(4096ull * 3072);
  bf16_t* ao    = vbuf;  // v row-major dead after transpose_v; reuse for attention out

  dim3 tb(32, 8);
  cvt_f32_to_bf16<<<8192, 256, 0, stream>>>(x, xb);
  transpose_w<<<dim3(24, 64), tb, 0, stream>>>(wq_down,  fw1,                 2048, 768);
  transpose_w<<<dim3(16, 64), tb, 0, stream>>>(wkv_down, fw1 + 768ull * 2048, 2048, 512);
  transpose_w<<<dim3(32, 64), tb, 0, stream>>>(wq_rope,  fw1 + 1280ull * 2048,2048, 1024);
  transpose_w<<<dim3(32, 64), tb, 0, stream>>>(wk_rope,  fw1 + 2304ull * 2048,2048, 1024);
  transpose_w<<<dim3(64, 24), tb, 0, stream>>>(wq_up,    wqu_t,               768, 2048);
  transpose_w<<<dim3(64, 16), tb, 0, stream>>>(wk_up,    fw2,                 512, 2048);
  transpose_w<<<dim3(96, 16), tb, 0, stream>>>(wv_up,    fw2 + 2048ull * 512, 512, 3072);
  transpose_w<<<dim3(64, 96), tb, 0, stream>>>(wo,       wo_t,                3072, 2048);

  // fused x-projections: qkvd + rope halves of qbuf/kbuf
  gemm_bt<4><<<dim3(26, 32), 256, 0, stream>>>(xb, 2048, fw1, qkvd, qbuf, kbuf, 2048, 0);
  // q_up: qbuf CD cols
  gemm_bt<2><<<dim3(16, 32), 256, 0, stream>>>(qkvd, 1280, wqu_t, qbuf, nullptr, nullptr, 768, 0);
  // k_up + v_up from latent slice
  gemm_bt<5><<<dim3(40, 32), 256, 0, stream>>>(qkvd + 768, 1280, fw2, kbuf, vbuf, nullptr, 512, 0);

  rope_inplace<<<8192, 256, 0, stream>>>(qbuf);
  rope_inplace<<<8192, 256, 0, stream>>>(kbuf);
  transpose_v_kernel<<<dim3(64, 6, 32), tb, 0, stream>>>(vbuf, vt);

  attn_kernel<<<dim3(16, 32), 256, 0, stream>>>(qbuf, kbuf, vt, ao);

  gemm_bt<1><<<dim3(16, 32), 256, 0, stream>>>(ao, 3072, wo_t, out, nullptr, nullptr, 3072, 2048);
}